// Round 4
// baseline (741.190 us; speedup 1.0000x reference)
//
#include <hip/hip_runtime.h>
#include <hip/hip_bf16.h>
#include <stdint.h>

// ---- problem constants ----
#define SEQ    98
#define DIMC   192
#define NHEADS 6
#define HDIM   32
#define NBATCH 2048
#define NWIN   512
#define SCALE  0.17677669529663687f   // 1/sqrt(32)

// ---- ws layout (bytes): tables only ----
#define OFF_QKVW  0u                       // bf16 [576][192]
#define OFF_PROJW 221184u                  // bf16 [192][192]
#define OFF_BIAS  294912u                  // bf16 [6][112][112]
#define OFF_FLAGS 445440u                  // int [512]

typedef __attribute__((ext_vector_type(4)))  float f32x4;
typedef __attribute__((ext_vector_type(8)))  short bf16x8;

static __device__ __forceinline__ uint16_t f2bf(float f) {
    uint32_t u = __builtin_bit_cast(uint32_t, f);
    u += 0x7fffu + ((u >> 16) & 1u);
    return (uint16_t)(u >> 16);
}
static __device__ __forceinline__ float bf2f(uint16_t h) {
    uint32_t u = ((uint32_t)h) << 16;
    return __builtin_bit_cast(float, u);
}
static __device__ __forceinline__ uint32_t cvtpk(float a, float b) {
    uint32_t d;
    asm("v_cvt_pk_bf16_f32 %0, %1, %2" : "=v"(d) : "v"(a), "v"(b));
    return d;
}

// ---------------- K0: weight conversion + bias gather ----------------
__global__ void __launch_bounds__(256) k_prep(
    const float* __restrict__ qkv_w, const float* __restrict__ proj_w,
    const float* __restrict__ bias_table, const int* __restrict__ rel_idx,
    uint16_t* __restrict__ qkv_wb, uint16_t* __restrict__ proj_wb,
    uint16_t* __restrict__ bias6b)
{
    int idx = blockIdx.x * 256 + threadIdx.x;   // 870*256 = 222720 exactly
    if (idx < 110592) {
        qkv_wb[idx] = f2bf(qkv_w[idx]);
    } else if (idx < 147456) {
        int t = idx - 110592;
        proj_wb[t] = f2bf(proj_w[t]);
    } else {
        int t = idx - 147456;                   // [6][112][112]
        int h = t / (112 * 112);
        int rr = t % (112 * 112);
        int i = rr / 112, j = rr % 112;
        float v = -1e30f;
        if (i < SEQ && j < SEQ) v = bias_table[rel_idx[i * SEQ + j] * NHEADS + h];
        bias6b[t] = f2bf(v);
    }
}

// ---------------- K0a: per-window mask-nonzero flags ----------------
__global__ void __launch_bounds__(256) k_flags(const float* __restrict__ mask,
                                               int* __restrict__ flags)
{
    int w = blockIdx.x;
    __shared__ int sf;
    if (threadIdx.x == 0) sf = 0;
    __syncthreads();
    const float* m = mask + (size_t)w * (SEQ * SEQ);
    int local = 0;
    for (int i = threadIdx.x; i < SEQ * SEQ; i += 256) local |= (m[i] != 0.0f);
    if (local) atomicOr(&sf, 1);
    __syncthreads();
    if (threadIdx.x == 0) flags[w] = sf;
}

// ---------------- K1: fully fused per-window kernel ----------------
// 512 threads = 8 waves, 1 block per window.
// Phases: stage x -> [per head-group g=0,1: QKV GEMM -> attention] -> proj.
__global__ void __launch_bounds__(512, 2) k_fused(
    const float* __restrict__ x, const float* __restrict__ qkv_b,
    const uint16_t* __restrict__ qkv_wb, const uint16_t* __restrict__ bias6b,
    const float* __restrict__ mask, const int* __restrict__ flags,
    const uint16_t* __restrict__ proj_wb, const float* __restrict__ proj_b,
    float* __restrict__ out)
{
    __shared__ uint16_t xs[98][200];       // 39200 B  (x in bf16)
    __shared__ uint16_t q_s[3][98][40];    // 23520 B
    __shared__ uint16_t k_s[3][98][40];    // 23520 B
    __shared__ uint16_t vT_s[3][32][136];  // 26112 B  (cols 98..135 zero)
    __shared__ uint16_t att_s[98][200];    // 39200 B
    __shared__ uint16_t ps[8][16][40];     // 10240 B  (per-wave P bounce)
    // total 161792 B <= 163840

    const int b = blockIdx.x, tid = threadIdx.x;
    const int lane = tid & 63, wave = tid >> 6;      // 8 waves
    const int l15 = lane & 15, lq = lane >> 4;
    const int wdx = b & (NWIN - 1);
    const int useMask = flags[wdx];
    const float* maskp = mask + (size_t)wdx * (SEQ * SEQ);

    // zero vT pad cols 98..135 (all 3 head slots; never overwritten later)
    for (int i = tid; i < 3 * 32 * 19; i += 512) {
        int hd = i / 19, c = 98 + (i % 19) * 2;
        *(uint32_t*)&vT_s[hd >> 5][hd & 31][c] = 0;
    }
    // stage x[b] fp32 -> bf16 LDS
    const float4* x4 = (const float4*)(x + (size_t)b * SEQ * DIMC);
    for (int i = tid; i < SEQ * DIMC / 4; i += 512) {   // 4704
        float4 v = x4[i];
        int row = i / 48, col = (i % 48) * 4;
        uint2 pk;
        pk.x = cvtpk(v.x, v.y);
        pk.y = cvtpk(v.z, v.w);
        *(uint2*)&xs[row][col] = pk;
    }
    __syncthreads();

    for (int g = 0; g < 2; g++) {
        if (g) __syncthreads();   // attn(g-1) readers done before qkv overwrite

        // ---- QKV GEMM for heads 3g..3g+2: 18 ot16-tiles x 7 mt ----
        // unit u = (ot, mt-half); 36 units over 8 waves
        for (int u = wave; u < 36; u += 8) {
            int ot = u >> 1, half = u & 1;
            int sec = ot / 6, rem = ot % 6, hl = rem >> 1, dh = rem & 1;
            int wrow = sec * 192 + (3 * g + hl) * 32 + dh * 16 + l15;
            const uint16_t* wp = qkv_wb + (size_t)wrow * DIMC + lq * 8;
            bf16x8 bfr[6];
            #pragma unroll
            for (int kk = 0; kk < 6; kk++) bfr[kk] = *(const bf16x8*)(wp + kk * 32);
            float qb = qkv_b[wrow];
            int mt0 = half ? 4 : 0, mt1 = half ? 7 : 4;
            for (int mt = mt0; mt < mt1; mt++) {
                int ar = mt * 16 + l15; if (ar > 97) ar = 97;
                bf16x8 afr[6];
                #pragma unroll
                for (int kk = 0; kk < 6; kk++)
                    afr[kk] = *(const bf16x8*)&xs[ar][kk * 32 + lq * 8];
                f32x4 acc = {0.f, 0.f, 0.f, 0.f};
                #pragma unroll
                for (int kk = 0; kk < 6; kk++)
                    acc = __builtin_amdgcn_mfma_f32_16x16x32_bf16(afr[kk], bfr[kk], acc, 0, 0, 0);
                #pragma unroll
                for (int r = 0; r < 4; r++) {
                    int row = mt * 16 + lq * 4 + r;
                    if (row < SEQ) {
                        uint16_t vv = f2bf(acc[r] + qb);
                        if (sec == 0)      q_s[hl][row][dh * 16 + l15] = vv;
                        else if (sec == 1) k_s[hl][row][dh * 16 + l15] = vv;
                        else               vT_s[hl][dh * 16 + l15][row] = vv;
                    }
                }
            }
        }
        __syncthreads();

        // ---- attention for heads 3g..3g+2: 21 (hl,mt) tiles ----
        for (int t = wave; t < 21; t += 8) {
            int hl = t / 7, mt = t % 7, H = 3 * g + hl;
            int qrow = mt * 16 + l15; if (qrow > 97) qrow = 97;
            bf16x8 aq = *(const bf16x8*)&q_s[hl][qrow][lq * 8];

            float p[7][4], rowmax[4], rowsum[4];
            #pragma unroll
            for (int r = 0; r < 4; r++) rowmax[r] = -3e38f;
            #pragma unroll
            for (int jt = 0; jt < 7; jt++) {
                int krow = jt * 16 + l15; if (krow > 97) krow = 97;
                bf16x8 bk = *(const bf16x8*)&k_s[hl][krow][lq * 8];
                f32x4 z = {0.f, 0.f, 0.f, 0.f};
                f32x4 s4 = __builtin_amdgcn_mfma_f32_16x16x32_bf16(aq, bk, z, 0, 0, 0);
                int j = jt * 16 + l15;
                #pragma unroll
                for (int r = 0; r < 4; r++) {
                    int i_ = mt * 16 + lq * 4 + r;
                    float s = s4[r] * SCALE + bf2f(bias6b[(H * 112 + i_) * 112 + j]);
                    if (useMask && i_ < SEQ && j < SEQ) s += maskp[i_ * SEQ + j];
                    p[jt][r] = s;
                    rowmax[r] = fmaxf(rowmax[r], s);
                }
            }
            #pragma unroll
            for (int r = 0; r < 4; r++) {
                float m = rowmax[r];
                m = fmaxf(m, __shfl_xor(m, 1));
                m = fmaxf(m, __shfl_xor(m, 2));
                m = fmaxf(m, __shfl_xor(m, 4));
                m = fmaxf(m, __shfl_xor(m, 8));
                rowmax[r] = m; rowsum[r] = 0.f;
            }
            #pragma unroll
            for (int jt = 0; jt < 7; jt++)
                #pragma unroll
                for (int r = 0; r < 4; r++) {
                    float e = __expf(p[jt][r] - rowmax[r]);
                    p[jt][r] = e; rowsum[r] += e;
                }
            #pragma unroll
            for (int r = 0; r < 4; r++) {
                float s2 = rowsum[r];
                s2 += __shfl_xor(s2, 1); s2 += __shfl_xor(s2, 2);
                s2 += __shfl_xor(s2, 4); s2 += __shfl_xor(s2, 8);
                rowsum[r] = 1.0f / s2;
            }

            // PV: K=112 padded to 128, 4 chunks of 32
            f32x4 o0 = {0.f,0.f,0.f,0.f}, o1 = {0.f,0.f,0.f,0.f};
            #pragma unroll
            for (int kk = 0; kk < 4; kk++) {
                #pragma unroll
                for (int r = 0; r < 4; r++) {
                    ps[wave][lq * 4 + r][l15]      = f2bf(p[2 * kk][r]);
                    ps[wave][lq * 4 + r][16 + l15] = f2bf(2 * kk + 1 < 7 ? p[2 * kk + 1][r] : 0.f);
                }
                bf16x8 ap  = *(const bf16x8*)&ps[wave][l15][lq * 8];
                bf16x8 bv0 = *(const bf16x8*)&vT_s[hl][l15][kk * 32 + lq * 8];
                bf16x8 bv1 = *(const bf16x8*)&vT_s[hl][16 + l15][kk * 32 + lq * 8];
                o0 = __builtin_amdgcn_mfma_f32_16x16x32_bf16(ap, bv0, o0, 0, 0, 0);
                o1 = __builtin_amdgcn_mfma_f32_16x16x32_bf16(ap, bv1, o1, 0, 0, 0);
            }
            #pragma unroll
            for (int r = 0; r < 4; r++) {
                int row = mt * 16 + lq * 4 + r;
                if (row < SEQ) {
                    att_s[row][H * HDIM + l15]      = f2bf(o0[r] * rowsum[r]);
                    att_s[row][H * HDIM + 16 + l15] = f2bf(o1[r] * rowsum[r]);
                }
            }
        }
    }
    __syncthreads();

    // ---- proj: out[b] = att @ proj_w^T + proj_b; 24 (ot,half) units ----
    for (int u = wave; u < 24; u += 8) {
        int ot = u >> 1, half = u & 1;
        const uint16_t* wp = proj_wb + (size_t)(ot * 16 + l15) * DIMC + lq * 8;
        bf16x8 bw[6];
        #pragma unroll
        for (int kk = 0; kk < 6; kk++) bw[kk] = *(const bf16x8*)(wp + kk * 32);
        float pb = proj_b[ot * 16 + l15];
        int mt0 = half ? 4 : 0, mt1 = half ? 7 : 4;
        for (int mt = mt0; mt < mt1; mt++) {
            int arow = mt * 16 + l15; if (arow > 97) arow = 97;
            bf16x8 aa[6];
            #pragma unroll
            for (int kk = 0; kk < 6; kk++)
                aa[kk] = *(const bf16x8*)&att_s[arow][kk * 32 + lq * 8];
            f32x4 acc = {0.f, 0.f, 0.f, 0.f};
            #pragma unroll
            for (int kk = 0; kk < 6; kk++)
                acc = __builtin_amdgcn_mfma_f32_16x16x32_bf16(aa[kk], bw[kk], acc, 0, 0, 0);
            #pragma unroll
            for (int r = 0; r < 4; r++) {
                int row = mt * 16 + lq * 4 + r;
                if (row < SEQ)
                    out[((size_t)b * SEQ + row) * DIMC + ot * 16 + l15] = acc[r] + pb;
            }
        }
    }
}

// ---------------- launch ----------------
extern "C" void kernel_launch(void* const* d_in, const int* in_sizes, int n_in,
                              void* d_out, int out_size, void* d_ws, size_t ws_size,
                              hipStream_t stream) {
    const float* x          = (const float*)d_in[0];
    const float* mask       = (const float*)d_in[1];
    const float* qkv_w      = (const float*)d_in[2];
    const float* qkv_b      = (const float*)d_in[3];
    const float* proj_w     = (const float*)d_in[4];
    const float* proj_b     = (const float*)d_in[5];
    const float* bias_table = (const float*)d_in[6];
    const int*   rel_idx    = (const int*)d_in[7];
    float* out = (float*)d_out;
    char*  ws  = (char*)d_ws;

    uint16_t* qkv_wb  = (uint16_t*)(ws + OFF_QKVW);
    uint16_t* proj_wb = (uint16_t*)(ws + OFF_PROJW);
    uint16_t* bias6b  = (uint16_t*)(ws + OFF_BIAS);
    int*      flags   = (int*)(ws + OFF_FLAGS);

    k_prep<<<870, 256, 0, stream>>>(qkv_w, proj_w, bias_table, rel_idx,
                                    qkv_wb, proj_wb, bias6b);
    k_flags<<<NWIN, 256, 0, stream>>>(mask, flags);
    k_fused<<<NBATCH, 512, 0, stream>>>(x, qkv_b, qkv_wb, bias6b, mask, flags,
                                        proj_wb, proj_b, out);
}